// Round 1
// baseline (1746.885 us; speedup 1.0000x reference)
//
#include <hip/hip_runtime.h>
#include <hip/hip_bf16.h>

// PointTransformerConv block, fp32 throughout.
//   K1: x1 = relu(x@W_in+b_in); a_src=x1@W_src; a_dst=x1@W_dst; v=x1@W_lin
//   K2: per-edge fused: delta-MLP, alpha-MLP, e=exp(alpha) (no max-subtraction
//       needed: ratio invariant, |alpha|~O(1)), atomic accumulate
//       numer[dst,c] += e*(v[src,c]+delta), denom[dst,c] += e
//   K3: out = relu((numer/max(denom,1e-16))@W_out + b_out)

#define LDT 68  // padded LDS row stride for transposed activation tile (bank spread + 16B align)

__global__ __launch_bounds__(256) void node_linear_kernel(
    const float* __restrict__ x,
    const float* __restrict__ W_in, const float* __restrict__ b_in,
    const float* __restrict__ W_lin, const float* __restrict__ W_src, const float* __restrict__ W_dst,
    float* __restrict__ a_src, float* __restrict__ a_dst, float* __restrict__ vv,
    int N)
{
  __shared__ float sWin[4096], sWs[4096], sWd[4096], sWl[4096], sb[64];
  int tid = threadIdx.x;
  for (int i = tid; i < 4096; i += 256) {
    sWin[i] = W_in[i]; sWs[i] = W_src[i]; sWd[i] = W_dst[i]; sWl[i] = W_lin[i];
  }
  if (tid < 64) sb[tid] = b_in[tid];
  __syncthreads();
  int lane = tid & 63;
  int wv   = tid >> 6;
  int nw   = gridDim.x * 4;
  for (int row = blockIdx.x * 4 + wv; row < N; row += nw) {
    float xv  = x[row * 64 + lane];
    float acc = sb[lane];
    #pragma unroll
    for (int k = 0; k < 64; k++) {
      float xk = __shfl(xv, k);
      acc = fmaf(xk, sWin[(k << 6) + lane], acc);
    }
    float x1 = fmaxf(acc, 0.f);
    float as = 0.f, ad = 0.f, vl = 0.f;
    #pragma unroll
    for (int k = 0; k < 64; k++) {
      float xk = __shfl(x1, k);
      as = fmaf(xk, sWs[(k << 6) + lane], as);
      ad = fmaf(xk, sWd[(k << 6) + lane], ad);
      vl = fmaf(xk, sWl[(k << 6) + lane], vl);
    }
    a_src[row * 64 + lane] = as;
    a_dst[row * 64 + lane] = ad;
    vv[row * 64 + lane]    = vl;
  }
}

__global__ __launch_bounds__(256) void edge_kernel(
    const float* __restrict__ pos, const int* __restrict__ ei,
    const float* __restrict__ a_src_g, const float* __restrict__ a_dst_g, const float* __restrict__ v_g,
    const float* __restrict__ pos_W1, const float* __restrict__ pos_b1,
    const float* __restrict__ pos_gg, const float* __restrict__ pos_beta,
    const float* __restrict__ pos_W2, const float* __restrict__ pos_b2,
    const float* __restrict__ att_W1, const float* __restrict__ att_b1,
    const float* __restrict__ att_gg, const float* __restrict__ att_beta,
    const float* __restrict__ att_W2, const float* __restrict__ att_b2,
    float* __restrict__ numer, float* __restrict__ denom,
    int N, int E, int Etot)
{
  __shared__ float sW2[4096], sA1[4096], sA2[4096];   // pos_W2, att_W1, att_W2
  __shared__ float sT[64 * LDT];                      // transposed activations [k][edge]
  __shared__ float sPW1[192];
  __shared__ float sPB1[64], sPG[64], sPBeta[64], sPB2[64];
  __shared__ float sAB1[64], sAG[64], sABeta[64], sAB2[64];
  __shared__ int   sS[64], sD[64];
  __shared__ float sPD[3][64];

  int tid = threadIdx.x;
  for (int i = tid; i < 4096; i += 256) { sW2[i] = pos_W2[i]; sA1[i] = att_W1[i]; sA2[i] = att_W2[i]; }
  for (int i = tid; i < 192;  i += 256) sPW1[i] = pos_W1[i];
  if (tid < 64) {
    sPB1[tid] = pos_b1[tid]; sPG[tid] = pos_gg[tid]; sPBeta[tid] = pos_beta[tid]; sPB2[tid] = pos_b2[tid];
    sAB1[tid] = att_b1[tid]; sAG[tid] = att_gg[tid]; sABeta[tid] = att_beta[tid]; sAB2[tid] = att_b2[tid];
  }

  const int cg = tid & 15;        // channel group: channels c0..c0+3
  const int eg = tid >> 4;        // edge group:    edges    e0..e0+3
  const int c0 = cg << 2;
  const int e0 = eg << 2;
  const int ntile = (Etot + 63) >> 6;

  for (int tile = blockIdx.x; tile < ntile; tile += gridDim.x) {
    const int ebase = tile << 6;
    __syncthreads();  // prev tile fully consumed (also covers initial weight staging)

    if (tid < 64) {
      int e = ebase + tid;
      int s = 0, d = 0;
      if (e < E)         { s = ei[e]; d = ei[E + e]; }
      else if (e < Etot) { s = e - E; d = s; }
      sS[tid] = s; sD[tid] = d;
      sPD[0][tid] = pos[d * 3 + 0] - pos[s * 3 + 0];
      sPD[1][tid] = pos[d * 3 + 1] - pos[s * 3 + 1];
      sPD[2][tid] = pos[d * 3 + 2] - pos[s * 3 + 2];
    }
    __syncthreads();

    // ---- Phase A: h = relu(LN(pd @ pos_W1 + pos_b1)) -> sT (transposed) ----
    {
      float h[4][4];
      #pragma unroll
      for (int i = 0; i < 4; i++) {
        float p0 = sPD[0][e0 + i], p1 = sPD[1][e0 + i], p2 = sPD[2][e0 + i];
        #pragma unroll
        for (int j = 0; j < 4; j++) {
          int c = c0 + j;
          h[i][j] = fmaf(p0, sPW1[c], fmaf(p1, sPW1[64 + c], fmaf(p2, sPW1[128 + c], sPB1[c])));
        }
      }
      #pragma unroll
      for (int i = 0; i < 4; i++) {
        float s = h[i][0] + h[i][1] + h[i][2] + h[i][3];
        s += __shfl_xor(s, 1); s += __shfl_xor(s, 2); s += __shfl_xor(s, 4); s += __shfl_xor(s, 8);
        float m = s * (1.f / 64.f);
        float q = 0.f;
        #pragma unroll
        for (int j = 0; j < 4; j++) { float dd = h[i][j] - m; q = fmaf(dd, dd, q); }
        q += __shfl_xor(q, 1); q += __shfl_xor(q, 2); q += __shfl_xor(q, 4); q += __shfl_xor(q, 8);
        float rs = rsqrtf(q * (1.f / 64.f) + 1e-5f);
        #pragma unroll
        for (int j = 0; j < 4; j++) {
          int c = c0 + j;
          h[i][j] = fmaxf(fmaf((h[i][j] - m) * rs, sPG[c], sPBeta[c]), 0.f);
        }
      }
      #pragma unroll
      for (int j = 0; j < 4; j++)
        #pragma unroll
        for (int i = 0; i < 4; i++)
          sT[(c0 + j) * LDT + e0 + i] = h[i][j];
    }
    __syncthreads();

    // ---- Phase B: delta = hR @ pos_W2 + pos_b2 (4x4 per thread) ----
    float del[4][4];
    #pragma unroll
    for (int i = 0; i < 4; i++)
      #pragma unroll
      for (int j = 0; j < 4; j++) del[i][j] = 0.f;
    #pragma unroll 8
    for (int k = 0; k < 64; k++) {
      const float4 a4 = *(const float4*)&sT[k * LDT + e0];
      const float4 b4 = *(const float4*)&sW2[(k << 6) + c0];
      const float av[4] = {a4.x, a4.y, a4.z, a4.w};
      const float bv[4] = {b4.x, b4.y, b4.z, b4.w};
      #pragma unroll
      for (int i = 0; i < 4; i++)
        #pragma unroll
        for (int j = 0; j < 4; j++) del[i][j] = fmaf(av[i], bv[j], del[i][j]);
    }
    #pragma unroll
    for (int i = 0; i < 4; i++)
      #pragma unroll
      for (int j = 0; j < 4; j++) del[i][j] += sPB2[c0 + j];

    __syncthreads();  // everyone done reading sT

    // ---- Phase C: attin = a_dst[d] - a_src[s] + delta -> sT (transposed) ----
    #pragma unroll
    for (int i = 0; i < 4; i++) {
      int s = sS[e0 + i], d = sD[e0 + i];
      const float4 ad = *(const float4*)&a_dst_g[d * 64 + c0];
      const float4 as = *(const float4*)&a_src_g[s * 64 + c0];
      sT[(c0 + 0) * LDT + e0 + i] = ad.x - as.x + del[i][0];
      sT[(c0 + 1) * LDT + e0 + i] = ad.y - as.y + del[i][1];
      sT[(c0 + 2) * LDT + e0 + i] = ad.z - as.z + del[i][2];
      sT[(c0 + 3) * LDT + e0 + i] = ad.w - as.w + del[i][3];
    }
    __syncthreads();

    // ---- Phase D: h2 = relu(LN(attin @ att_W1 + att_b1)) ----
    float h2[4][4];
    #pragma unroll
    for (int i = 0; i < 4; i++)
      #pragma unroll
      for (int j = 0; j < 4; j++) h2[i][j] = 0.f;
    #pragma unroll 8
    for (int k = 0; k < 64; k++) {
      const float4 a4 = *(const float4*)&sT[k * LDT + e0];
      const float4 b4 = *(const float4*)&sA1[(k << 6) + c0];
      const float av[4] = {a4.x, a4.y, a4.z, a4.w};
      const float bv[4] = {b4.x, b4.y, b4.z, b4.w};
      #pragma unroll
      for (int i = 0; i < 4; i++)
        #pragma unroll
        for (int j = 0; j < 4; j++) h2[i][j] = fmaf(av[i], bv[j], h2[i][j]);
    }
    #pragma unroll
    for (int i = 0; i < 4; i++) {
      #pragma unroll
      for (int j = 0; j < 4; j++) h2[i][j] += sAB1[c0 + j];
      float s = h2[i][0] + h2[i][1] + h2[i][2] + h2[i][3];
      s += __shfl_xor(s, 1); s += __shfl_xor(s, 2); s += __shfl_xor(s, 4); s += __shfl_xor(s, 8);
      float m = s * (1.f / 64.f);
      float q = 0.f;
      #pragma unroll
      for (int j = 0; j < 4; j++) { float dd = h2[i][j] - m; q = fmaf(dd, dd, q); }
      q += __shfl_xor(q, 1); q += __shfl_xor(q, 2); q += __shfl_xor(q, 4); q += __shfl_xor(q, 8);
      float rs = rsqrtf(q * (1.f / 64.f) + 1e-5f);
      #pragma unroll
      for (int j = 0; j < 4; j++) {
        int c = c0 + j;
        h2[i][j] = fmaxf(fmaf((h2[i][j] - m) * rs, sAG[c], sABeta[c]), 0.f);
      }
    }
    __syncthreads();  // done reading sT (phase D)
    #pragma unroll
    for (int j = 0; j < 4; j++)
      #pragma unroll
      for (int i = 0; i < 4; i++)
        sT[(c0 + j) * LDT + e0 + i] = h2[i][j];
    __syncthreads();

    // ---- Phase E: alpha = h2r @ att_W2 (+b2 at use); accumulate outputs ----
    float al[4][4];
    #pragma unroll
    for (int i = 0; i < 4; i++)
      #pragma unroll
      for (int j = 0; j < 4; j++) al[i][j] = 0.f;
    #pragma unroll 8
    for (int k = 0; k < 64; k++) {
      const float4 a4 = *(const float4*)&sT[k * LDT + e0];
      const float4 b4 = *(const float4*)&sA2[(k << 6) + c0];
      const float av[4] = {a4.x, a4.y, a4.z, a4.w};
      const float bv[4] = {b4.x, b4.y, b4.z, b4.w};
      #pragma unroll
      for (int i = 0; i < 4; i++)
        #pragma unroll
        for (int j = 0; j < 4; j++) al[i][j] = fmaf(av[i], bv[j], al[i][j]);
    }

    #pragma unroll
    for (int i = 0; i < 4; i++) {
      int eglob = ebase + e0 + i;
      if (eglob >= Etot) continue;
      int s = sS[e0 + i], d = sD[e0 + i];
      const float4 vv = *(const float4*)&v_g[s * 64 + c0];
      const float vvv[4] = {vv.x, vv.y, vv.z, vv.w};
      #pragma unroll
      for (int j = 0; j < 4; j++) {
        float ee = __expf(al[i][j] + sAB2[c0 + j]);
        atomicAdd(&numer[d * 64 + c0 + j], ee * (vvv[j] + del[i][j]));
        atomicAdd(&denom[d * 64 + c0 + j], ee);
      }
    }
  }
}

__global__ __launch_bounds__(256) void out_linear_kernel(
    const float* __restrict__ numer, const float* __restrict__ denom,
    const float* __restrict__ W_out, const float* __restrict__ b_out,
    float* __restrict__ out, int N)
{
  __shared__ float sW[4096], sb[64];
  int tid = threadIdx.x;
  for (int i = tid; i < 4096; i += 256) sW[i] = W_out[i];
  if (tid < 64) sb[tid] = b_out[tid];
  __syncthreads();
  int lane = tid & 63, wv = tid >> 6;
  int nw = gridDim.x * 4;
  for (int row = blockIdx.x * 4 + wv; row < N; row += nw) {
    float m = numer[row * 64 + lane] / fmaxf(denom[row * 64 + lane], 1e-16f);
    float acc = sb[lane];
    #pragma unroll
    for (int k = 0; k < 64; k++) {
      float mk = __shfl(m, k);
      acc = fmaf(mk, sW[(k << 6) + lane], acc);
    }
    out[row * 64 + lane] = fmaxf(acc, 0.f);
  }
}

extern "C" void kernel_launch(void* const* d_in, const int* in_sizes, int n_in,
                              void* d_out, int out_size, void* d_ws, size_t ws_size,
                              hipStream_t stream) {
  (void)n_in; (void)out_size; (void)ws_size;
  const float* x        = (const float*)d_in[0];
  const float* pos      = (const float*)d_in[1];
  const int*   ei       = (const int*)  d_in[2];
  const float* W_in     = (const float*)d_in[3];
  const float* b_in     = (const float*)d_in[4];
  const float* W_lin    = (const float*)d_in[5];
  const float* W_src    = (const float*)d_in[6];
  const float* W_dst    = (const float*)d_in[7];
  const float* pos_W1   = (const float*)d_in[8];
  const float* pos_b1   = (const float*)d_in[9];
  const float* pos_g    = (const float*)d_in[10];
  const float* pos_beta = (const float*)d_in[11];
  const float* pos_W2   = (const float*)d_in[12];
  const float* pos_b2   = (const float*)d_in[13];
  const float* att_W1   = (const float*)d_in[14];
  const float* att_b1   = (const float*)d_in[15];
  const float* att_g    = (const float*)d_in[16];
  const float* att_beta = (const float*)d_in[17];
  const float* att_W2   = (const float*)d_in[18];
  const float* att_b2   = (const float*)d_in[19];
  const float* W_out    = (const float*)d_in[20];
  const float* b_out    = (const float*)d_in[21];

  const int N    = in_sizes[0] / 64;
  const int E    = in_sizes[2] / 2;
  const int Etot = E + N;
  const size_t N64 = (size_t)N * 64;

  float* a_src = (float*)d_ws;
  float* a_dst = a_src + N64;
  float* v     = a_dst + N64;
  float* numer = v + N64;
  float* denom = numer + N64;

  hipMemsetAsync(numer, 0, 2 * N64 * sizeof(float), stream);

  node_linear_kernel<<<1024, 256, 0, stream>>>(x, W_in, b_in, W_lin, W_src, W_dst,
                                               a_src, a_dst, v, N);

  const int ntile = (Etot + 63) / 64;
  const int nblk  = ntile < 2048 ? ntile : 2048;
  edge_kernel<<<nblk, 256, 0, stream>>>(pos, ei, a_src, a_dst, v,
      pos_W1, pos_b1, pos_g, pos_beta, pos_W2, pos_b2,
      att_W1, att_b1, att_g, att_beta, att_W2, att_b2,
      numer, denom, N, E, Etot);

  out_linear_kernel<<<1024, 256, 0, stream>>>(numer, denom, W_out, b_out, (float*)d_out, N);
}

// Round 2
// 965.670 us; speedup vs baseline: 1.8090x; 1.8090x over previous
//
#include <hip/hip_runtime.h>
#include <hip/hip_bf16.h>

// PointTransformerConv block.
//   CSR: counting-sort edges by dst (hist -> scan -> scatter) so the edge
//        kernel sees dst-sorted tiles -> segmented LDS reduction -> ~13x
//        fewer global fp32 atomics.
//   K1: x1 = relu(x@W_in+b_in); a_src=x1@W_src; a_dst=x1@W_dst; v=x1@W_lin
//   K2: per-edge fused: delta-MLP, alpha-MLP, e=exp(alpha) (softmax ratio is
//       shift-invariant; |alpha|~O(1) so no max needed), segment-reduce,
//       accumulate numer[dst,c] += e*(v+delta), denom[dst,c] += e.
//       Edge-GEMM weights + activation tile in bf16 LDS (LDS 45KB -> 3 blk/CU).
//   K3: out = relu((numer/max(denom,1e-16))@W_out + b_out)

#define LDT2 68     // bf16 elems per sT row (pad); P = LDT2/2 = 34 uints
#define STP  34
#define MAXSEG 16

__device__ __forceinline__ unsigned short f2b(float f) {
  union { __hip_bfloat16 h; unsigned short u; } c;
  c.h = __float2bfloat16(f);
  return c.u;
}
__device__ __forceinline__ unsigned int pack2(float a, float b) {
  return (unsigned int)f2b(a) | ((unsigned int)f2b(b) << 16);
}
__device__ __forceinline__ void unpack2(unsigned int u, float& a, float& b) {
  union { unsigned int x; float f; } t0, t1;
  t0.x = u << 16; t1.x = u & 0xffff0000u;
  a = t0.f; b = t1.f;
}

// ---------------- node linears ----------------
__global__ __launch_bounds__(256) void node_linear_kernel(
    const float* __restrict__ x,
    const float* __restrict__ W_in, const float* __restrict__ b_in,
    const float* __restrict__ W_lin, const float* __restrict__ W_src, const float* __restrict__ W_dst,
    float* __restrict__ a_src, float* __restrict__ a_dst, float* __restrict__ vv,
    int N)
{
  __shared__ float sWin[4096], sWs[4096], sWd[4096], sWl[4096], sb[64];
  int tid = threadIdx.x;
  for (int i = tid; i < 4096; i += 256) {
    sWin[i] = W_in[i]; sWs[i] = W_src[i]; sWd[i] = W_dst[i]; sWl[i] = W_lin[i];
  }
  if (tid < 64) sb[tid] = b_in[tid];
  __syncthreads();
  int lane = tid & 63;
  int wv   = tid >> 6;
  int nw   = gridDim.x * 4;
  for (int row = blockIdx.x * 4 + wv; row < N; row += nw) {
    float xv  = x[row * 64 + lane];
    float acc = sb[lane];
    #pragma unroll
    for (int k = 0; k < 64; k++) {
      float xk = __shfl(xv, k);
      acc = fmaf(xk, sWin[(k << 6) + lane], acc);
    }
    float x1 = fmaxf(acc, 0.f);
    float as = 0.f, ad = 0.f, vl = 0.f;
    #pragma unroll
    for (int k = 0; k < 64; k++) {
      float xk = __shfl(x1, k);
      as = fmaf(xk, sWs[(k << 6) + lane], as);
      ad = fmaf(xk, sWd[(k << 6) + lane], ad);
      vl = fmaf(xk, sWl[(k << 6) + lane], vl);
    }
    a_src[row * 64 + lane] = as;
    a_dst[row * 64 + lane] = ad;
    vv[row * 64 + lane]    = vl;
  }
}

// ---------------- CSR build ----------------
__global__ void hist_kernel(const int* __restrict__ ei, int* __restrict__ deg, int E, int Etot) {
  int stride = gridDim.x * blockDim.x;
  for (int e = blockIdx.x * blockDim.x + threadIdx.x; e < Etot; e += stride) {
    int d = (e < E) ? ei[E + e] : (e - E);
    atomicAdd(&deg[d], 1);
  }
}

__global__ __launch_bounds__(256) void scanA_kernel(const int* __restrict__ deg, int* __restrict__ chunkSum, int N) {
  __shared__ int s[256];
  int i = blockIdx.x * 256 + threadIdx.x;
  s[threadIdx.x] = (i < N) ? deg[i] : 0;
  __syncthreads();
  for (int off = 128; off > 0; off >>= 1) {
    if (threadIdx.x < off) s[threadIdx.x] += s[threadIdx.x + off];
    __syncthreads();
  }
  if (threadIdx.x == 0) chunkSum[blockIdx.x] = s[0];
}

__global__ __launch_bounds__(256) void scanB_kernel(const int* __restrict__ chunkSum, int* __restrict__ chunkPre, int nchunk) {
  __shared__ int s[256];
  int t = threadIdx.x;
  int v = (t < nchunk) ? chunkSum[t] : 0;
  s[t] = v; __syncthreads();
  for (int off = 1; off < 256; off <<= 1) {
    int x = (t >= off) ? s[t - off] : 0;
    __syncthreads();
    s[t] += x;
    __syncthreads();
  }
  if (t < nchunk) chunkPre[t] = s[t] - v;  // exclusive
}

__global__ __launch_bounds__(256) void scanC_kernel(const int* __restrict__ deg, const int* __restrict__ chunkPre,
                                                    int* __restrict__ cursor, int N) {
  __shared__ int s[256];
  int t = threadIdx.x;
  int i = blockIdx.x * 256 + t;
  int v = (i < N) ? deg[i] : 0;
  s[t] = v; __syncthreads();
  for (int off = 1; off < 256; off <<= 1) {
    int x = (t >= off) ? s[t - off] : 0;
    __syncthreads();
    s[t] += x;
    __syncthreads();
  }
  if (i < N) cursor[i] = chunkPre[blockIdx.x] + s[t] - v;
}

__global__ void scatter_kernel(const int* __restrict__ ei, int* __restrict__ cursor, int* __restrict__ perm,
                               int E, int Etot) {
  int stride = gridDim.x * blockDim.x;
  for (int e = blockIdx.x * blockDim.x + threadIdx.x; e < Etot; e += stride) {
    int d = (e < E) ? ei[E + e] : (e - E);
    int p = atomicAdd(&cursor[d], 1);
    perm[p] = e;
  }
}

// ---------------- fused edge kernel ----------------
__global__ __launch_bounds__(256, 3) void edge_kernel(
    const float* __restrict__ pos, const int* __restrict__ ei, const int* __restrict__ perm,
    const float* __restrict__ a_src_g, const float* __restrict__ a_dst_g, const float* __restrict__ v_g,
    const float* __restrict__ pos_W1, const float* __restrict__ pos_b1,
    const float* __restrict__ pos_gg, const float* __restrict__ pos_beta,
    const float* __restrict__ pos_W2, const float* __restrict__ pos_b2,
    const float* __restrict__ att_W1, const float* __restrict__ att_b1,
    const float* __restrict__ att_gg, const float* __restrict__ att_beta,
    const float* __restrict__ att_W2, const float* __restrict__ att_b2,
    float* __restrict__ numer, float* __restrict__ denom,
    int E, int Etot)
{
  __shared__ unsigned int sW2u[2048], sA1u[2048], sA2u[2048];  // bf16-packed [k][c/2]
  __shared__ unsigned int sTu[64 * STP];                       // bf16-packed [c][e/2]
  __shared__ float sAccN[MAXSEG * 64], sAccD[MAXSEG * 64];
  __shared__ float sPW1[192];
  __shared__ float sPB1[64], sPG[64], sPBeta[64], sPB2[64];
  __shared__ float sAB1[64], sAG[64], sABeta[64], sAB2[64];
  __shared__ int   sS[64], sD[64], sSeg[64];
  __shared__ int   sUd[MAXSEG];
  __shared__ int   sNseg;
  __shared__ float sPD[3][64];

  int tid = threadIdx.x;
  {
    const float2* w2 = (const float2*)pos_W2;
    const float2* a1 = (const float2*)att_W1;
    const float2* a2 = (const float2*)att_W2;
    for (int i = tid; i < 2048; i += 256) {
      float2 t;
      t = w2[i]; sW2u[i] = pack2(t.x, t.y);
      t = a1[i]; sA1u[i] = pack2(t.x, t.y);
      t = a2[i]; sA2u[i] = pack2(t.x, t.y);
    }
  }
  for (int i = tid; i < 192; i += 256) sPW1[i] = pos_W1[i];
  if (tid < 64) {
    sPB1[tid] = pos_b1[tid]; sPG[tid] = pos_gg[tid]; sPBeta[tid] = pos_beta[tid]; sPB2[tid] = pos_b2[tid];
    sAB1[tid] = att_b1[tid]; sAG[tid] = att_gg[tid]; sABeta[tid] = att_beta[tid]; sAB2[tid] = att_b2[tid];
  }

  const int cg = tid & 15;
  const int eg = tid >> 4;
  const int c0 = cg << 2;
  const int e0 = eg << 2;
  const int ntile = (Etot + 63) >> 6;

  for (int tile = blockIdx.x; tile < ntile; tile += gridDim.x) {
    const int ebase = tile << 6;
    __syncthreads();  // prev tile fully flushed (also covers initial staging)

    for (int i = tid; i < MAXSEG * 64; i += 256) { sAccN[i] = 0.f; sAccD[i] = 0.f; }

    if (tid < 64) {
      int slot = ebase + tid;
      int s = 0, d = -1;
      if (slot < Etot) {
        int e = perm[slot];
        if (e < E) { s = ei[e]; d = ei[E + e]; }
        else       { s = e - E; d = s; }
      }
      sS[tid] = s; sD[tid] = d;
      int dm = d < 0 ? 0 : d;
      sPD[0][tid] = pos[dm * 3 + 0] - pos[s * 3 + 0];
      sPD[1][tid] = pos[dm * 3 + 1] - pos[s * 3 + 1];
      sPD[2][tid] = pos[dm * 3 + 2] - pos[s * 3 + 2];
    }
    __syncthreads();

    if (tid < 64) {  // whole wave 0: segment ids via ballot
      bool valid = sD[tid] >= 0;
      bool flag  = valid && (tid == 0 || sD[tid] != sD[tid - 1]);
      unsigned long long m = __ballot(flag);
      int cnt = __popcll(m << (63 - tid));   // flags at positions <= tid
      sSeg[tid] = valid ? (cnt - 1) : -1;
      if (flag && (cnt - 1) < MAXSEG) sUd[cnt - 1] = sD[tid];
      if (tid == 0) sNseg = __popcll(m);
    }
    __syncthreads();

    // ---- Phase A: h = relu(LN(pd @ pos_W1 + pos_b1)) -> sTu ----
    {
      float h[4][4];
      #pragma unroll
      for (int i = 0; i < 4; i++) {
        float p0 = sPD[0][e0 + i], p1 = sPD[1][e0 + i], p2 = sPD[2][e0 + i];
        #pragma unroll
        for (int j = 0; j < 4; j++) {
          int c = c0 + j;
          h[i][j] = fmaf(p0, sPW1[c], fmaf(p1, sPW1[64 + c], fmaf(p2, sPW1[128 + c], sPB1[c])));
        }
      }
      #pragma unroll
      for (int i = 0; i < 4; i++) {
        float s = h[i][0] + h[i][1] + h[i][2] + h[i][3];
        s += __shfl_xor(s, 1); s += __shfl_xor(s, 2); s += __shfl_xor(s, 4); s += __shfl_xor(s, 8);
        float m = s * (1.f / 64.f);
        float q = 0.f;
        #pragma unroll
        for (int j = 0; j < 4; j++) { float dd = h[i][j] - m; q = fmaf(dd, dd, q); }
        q += __shfl_xor(q, 1); q += __shfl_xor(q, 2); q += __shfl_xor(q, 4); q += __shfl_xor(q, 8);
        float rs = rsqrtf(q * (1.f / 64.f) + 1e-5f);
        #pragma unroll
        for (int j = 0; j < 4; j++) {
          int c = c0 + j;
          h[i][j] = fmaxf(fmaf((h[i][j] - m) * rs, sPG[c], sPBeta[c]), 0.f);
        }
      }
      #pragma unroll
      for (int j = 0; j < 4; j++)
        #pragma unroll
        for (int i = 0; i < 4; i += 2)
          sTu[(c0 + j) * STP + ((e0 + i) >> 1)] = pack2(h[i][j], h[i + 1][j]);
    }
    __syncthreads();

    // ---- Phase B: delta = hT @ pos_W2 + pos_b2 ----
    float del[4][4];
    #pragma unroll
    for (int i = 0; i < 4; i++)
      #pragma unroll
      for (int j = 0; j < 4; j++) del[i][j] = 0.f;
    #pragma unroll 8
    for (int k = 0; k < 64; k++) {
      uint2 a = *(const uint2*)&sTu[k * STP + (e0 >> 1)];
      uint2 b = *(const uint2*)&sW2u[k * 32 + (c0 >> 1)];
      float av[4], bv[4];
      unpack2(a.x, av[0], av[1]); unpack2(a.y, av[2], av[3]);
      unpack2(b.x, bv[0], bv[1]); unpack2(b.y, bv[2], bv[3]);
      #pragma unroll
      for (int i = 0; i < 4; i++)
        #pragma unroll
        for (int j = 0; j < 4; j++) del[i][j] = fmaf(av[i], bv[j], del[i][j]);
    }
    #pragma unroll
    for (int i = 0; i < 4; i++)
      #pragma unroll
      for (int j = 0; j < 4; j++) del[i][j] += sPB2[c0 + j];
    __syncthreads();  // done reading sTu

    // ---- Phase C: attin = a_dst[d] - a_src[s] + delta -> sTu ----
    {
      float att[4][4];
      #pragma unroll
      for (int i = 0; i < 4; i++) {
        int s = sS[e0 + i], d = sD[e0 + i];
        int dm = d < 0 ? 0 : d;
        const float4 ad = *(const float4*)&a_dst_g[(size_t)dm * 64 + c0];
        const float4 as = *(const float4*)&a_src_g[(size_t)s  * 64 + c0];
        att[i][0] = ad.x - as.x + del[i][0];
        att[i][1] = ad.y - as.y + del[i][1];
        att[i][2] = ad.z - as.z + del[i][2];
        att[i][3] = ad.w - as.w + del[i][3];
      }
      #pragma unroll
      for (int j = 0; j < 4; j++)
        #pragma unroll
        for (int i = 0; i < 4; i += 2)
          sTu[(c0 + j) * STP + ((e0 + i) >> 1)] = pack2(att[i][j], att[i + 1][j]);
    }
    __syncthreads();

    // ---- Phase D: h2 = relu(LN(attin @ att_W1 + att_b1)) -> sTu ----
    float h2[4][4];
    #pragma unroll
    for (int i = 0; i < 4; i++)
      #pragma unroll
      for (int j = 0; j < 4; j++) h2[i][j] = 0.f;
    #pragma unroll 8
    for (int k = 0; k < 64; k++) {
      uint2 a = *(const uint2*)&sTu[k * STP + (e0 >> 1)];
      uint2 b = *(const uint2*)&sA1u[k * 32 + (c0 >> 1)];
      float av[4], bv[4];
      unpack2(a.x, av[0], av[1]); unpack2(a.y, av[2], av[3]);
      unpack2(b.x, bv[0], bv[1]); unpack2(b.y, bv[2], bv[3]);
      #pragma unroll
      for (int i = 0; i < 4; i++)
        #pragma unroll
        for (int j = 0; j < 4; j++) h2[i][j] = fmaf(av[i], bv[j], h2[i][j]);
    }
    #pragma unroll
    for (int i = 0; i < 4; i++) {
      #pragma unroll
      for (int j = 0; j < 4; j++) h2[i][j] += sAB1[c0 + j];
      float s = h2[i][0] + h2[i][1] + h2[i][2] + h2[i][3];
      s += __shfl_xor(s, 1); s += __shfl_xor(s, 2); s += __shfl_xor(s, 4); s += __shfl_xor(s, 8);
      float m = s * (1.f / 64.f);
      float q = 0.f;
      #pragma unroll
      for (int j = 0; j < 4; j++) { float dd = h2[i][j] - m; q = fmaf(dd, dd, q); }
      q += __shfl_xor(q, 1); q += __shfl_xor(q, 2); q += __shfl_xor(q, 4); q += __shfl_xor(q, 8);
      float rs = rsqrtf(q * (1.f / 64.f) + 1e-5f);
      #pragma unroll
      for (int j = 0; j < 4; j++) {
        int c = c0 + j;
        h2[i][j] = fmaxf(fmaf((h2[i][j] - m) * rs, sAG[c], sABeta[c]), 0.f);
      }
    }
    __syncthreads();  // done reading sTu (phase D)
    #pragma unroll
    for (int j = 0; j < 4; j++)
      #pragma unroll
      for (int i = 0; i < 4; i += 2)
        sTu[(c0 + j) * STP + ((e0 + i) >> 1)] = pack2(h2[i][j], h2[i + 1][j]);
    __syncthreads();

    // ---- Phase E: alpha = h2 @ att_W2; run-reduce + segmented accumulate ----
    float al[4][4];
    #pragma unroll
    for (int i = 0; i < 4; i++)
      #pragma unroll
      for (int j = 0; j < 4; j++) al[i][j] = 0.f;
    #pragma unroll 8
    for (int k = 0; k < 64; k++) {
      uint2 a = *(const uint2*)&sTu[k * STP + (e0 >> 1)];
      uint2 b = *(const uint2*)&sA2u[k * 32 + (c0 >> 1)];
      float av[4], bv[4];
      unpack2(a.x, av[0], av[1]); unpack2(a.y, av[2], av[3]);
      unpack2(b.x, bv[0], bv[1]); unpack2(b.y, bv[2], bv[3]);
      #pragma unroll
      for (int i = 0; i < 4; i++)
        #pragma unroll
        for (int j = 0; j < 4; j++) al[i][j] = fmaf(av[i], bv[j], al[i][j]);
    }

    {
      int curseg = -1, curd = 0;
      float aN[4] = {0.f, 0.f, 0.f, 0.f}, aD[4] = {0.f, 0.f, 0.f, 0.f};
      #pragma unroll
      for (int i = 0; i < 4; i++) {
        int slot = e0 + i;
        int d = sD[slot];
        if (d < 0) continue;
        int seg = sSeg[slot];
        if (seg != curseg) {
          if (curseg >= 0) {
            if (curseg < MAXSEG) {
              #pragma unroll
              for (int j = 0; j < 4; j++) {
                atomicAdd(&sAccN[curseg * 64 + c0 + j], aN[j]);
                atomicAdd(&sAccD[curseg * 64 + c0 + j], aD[j]);
              }
            } else {
              #pragma unroll
              for (int j = 0; j < 4; j++) {
                atomicAdd(&numer[(size_t)curd * 64 + c0 + j], aN[j]);
                atomicAdd(&denom[(size_t)curd * 64 + c0 + j], aD[j]);
              }
            }
          }
          curseg = seg; curd = d;
          #pragma unroll
          for (int j = 0; j < 4; j++) { aN[j] = 0.f; aD[j] = 0.f; }
        }
        const float4 vv = *(const float4*)&v_g[(size_t)sS[slot] * 64 + c0];
        const float vvv[4] = {vv.x, vv.y, vv.z, vv.w};
        #pragma unroll
        for (int j = 0; j < 4; j++) {
          float ee = __expf(al[i][j] + sAB2[c0 + j]);
          aN[j] = fmaf(ee, vvv[j] + del[i][j], aN[j]);
          aD[j] += ee;
        }
      }
      if (curseg >= 0) {
        if (curseg < MAXSEG) {
          #pragma unroll
          for (int j = 0; j < 4; j++) {
            atomicAdd(&sAccN[curseg * 64 + c0 + j], aN[j]);
            atomicAdd(&sAccD[curseg * 64 + c0 + j], aD[j]);
          }
        } else {
          #pragma unroll
          for (int j = 0; j < 4; j++) {
            atomicAdd(&numer[(size_t)curd * 64 + c0 + j], aN[j]);
            atomicAdd(&denom[(size_t)curd * 64 + c0 + j], aD[j]);
          }
        }
      }
    }
    __syncthreads();

    // ---- flush per-tile segment accumulators to global ----
    int nseg = sNseg; if (nseg > MAXSEG) nseg = MAXSEG;
    for (int idx = tid; idx < nseg * 64; idx += 256) {
      int seg = idx >> 6, c = idx & 63;
      int d = sUd[seg];
      atomicAdd(&numer[(size_t)d * 64 + c], sAccN[idx]);
      atomicAdd(&denom[(size_t)d * 64 + c], sAccD[idx]);
    }
  }
}

// ---------------- output linear ----------------
__global__ __launch_bounds__(256) void out_linear_kernel(
    const float* __restrict__ numer, const float* __restrict__ denom,
    const float* __restrict__ W_out, const float* __restrict__ b_out,
    float* __restrict__ out, int N)
{
  __shared__ float sW[4096], sb[64];
  int tid = threadIdx.x;
  for (int i = tid; i < 4096; i += 256) sW[i] = W_out[i];
  if (tid < 64) sb[tid] = b_out[tid];
  __syncthreads();
  int lane = tid & 63, wv = tid >> 6;
  int nw = gridDim.x * 4;
  for (int row = blockIdx.x * 4 + wv; row < N; row += nw) {
    float m = numer[row * 64 + lane] / fmaxf(denom[row * 64 + lane], 1e-16f);
    float acc = sb[lane];
    #pragma unroll
    for (int k = 0; k < 64; k++) {
      float mk = __shfl(m, k);
      acc = fmaf(mk, sW[(k << 6) + lane], acc);
    }
    out[row * 64 + lane] = fmaxf(acc, 0.f);
  }
}

extern "C" void kernel_launch(void* const* d_in, const int* in_sizes, int n_in,
                              void* d_out, int out_size, void* d_ws, size_t ws_size,
                              hipStream_t stream) {
  (void)n_in; (void)out_size; (void)ws_size;
  const float* x        = (const float*)d_in[0];
  const float* pos      = (const float*)d_in[1];
  const int*   ei       = (const int*)  d_in[2];
  const float* W_in     = (const float*)d_in[3];
  const float* b_in     = (const float*)d_in[4];
  const float* W_lin    = (const float*)d_in[5];
  const float* W_src    = (const float*)d_in[6];
  const float* W_dst    = (const float*)d_in[7];
  const float* pos_W1   = (const float*)d_in[8];
  const float* pos_b1   = (const float*)d_in[9];
  const float* pos_g    = (const float*)d_in[10];
  const float* pos_beta = (const float*)d_in[11];
  const float* pos_W2   = (const float*)d_in[12];
  const float* pos_b2   = (const float*)d_in[13];
  const float* att_W1   = (const float*)d_in[14];
  const float* att_b1   = (const float*)d_in[15];
  const float* att_g    = (const float*)d_in[16];
  const float* att_beta = (const float*)d_in[17];
  const float* att_W2   = (const float*)d_in[18];
  const float* att_b2   = (const float*)d_in[19];
  const float* W_out    = (const float*)d_in[20];
  const float* b_out    = (const float*)d_in[21];

  const int N    = in_sizes[0] / 64;
  const int E    = in_sizes[2] / 2;
  const int Etot = E + N;
  const size_t N64 = (size_t)N * 64;

  float* a_src = (float*)d_ws;
  float* a_dst = a_src + N64;
  float* v     = a_dst + N64;
  float* numer = v + N64;
  float* denom = numer + N64;
  int* deg      = (int*)(denom + N64);
  int* cursor   = deg + N;
  int* chunkSum = cursor + N;
  int* chunkPre = chunkSum + 256;
  int* perm     = chunkPre + 256;

  const int nchunk = (N + 255) / 256;  // 196 for N=50000 (must be <= 256)

  hipMemsetAsync(deg, 0, (size_t)N * sizeof(int), stream);
  hipMemsetAsync(numer, 0, 2 * N64 * sizeof(float), stream);

  hist_kernel<<<1024, 256, 0, stream>>>(ei, deg, E, Etot);
  scanA_kernel<<<nchunk, 256, 0, stream>>>(deg, chunkSum, N);
  scanB_kernel<<<1, 256, 0, stream>>>(chunkSum, chunkPre, nchunk);
  scanC_kernel<<<nchunk, 256, 0, stream>>>(deg, chunkPre, cursor, N);
  scatter_kernel<<<1024, 256, 0, stream>>>(ei, cursor, perm, E, Etot);

  node_linear_kernel<<<1024, 256, 0, stream>>>(x, W_in, b_in, W_lin, W_src, W_dst,
                                               a_src, a_dst, v, N);

  const int ntile = (Etot + 63) / 64;
  const int nblk  = ntile < 2048 ? ntile : 2048;
  edge_kernel<<<nblk, 256, 0, stream>>>(pos, ei, perm, a_src, a_dst, v,
      pos_W1, pos_b1, pos_g, pos_beta, pos_W2, pos_b2,
      att_W1, att_b1, att_g, att_beta, att_W2, att_b2,
      numer, denom, E, Etot);

  out_linear_kernel<<<1024, 256, 0, stream>>>(numer, denom, W_out, b_out, (float*)d_out, N);
}

// Round 3
// 470.847 us; speedup vs baseline: 3.7101x; 2.0509x over previous
//
#include <hip/hip_runtime.h>
#include <hip/hip_bf16.h>

// PointTransformerConv block, MFMA edition.
//   CSR counting-sort by dst -> edge tiles are dst-sorted -> segmented LDS
//   reduction (few global atomics).
//   All 64x64x64 GEMMs (node: in/src/dst/lin + out; edge: posW2/attW1/attW2)
//   run on mfma_f32_16x16x32_bf16. Activations stored [row][k] bf16 in LDS
//   with XOR swizzle byte^=((row&7)<<4); weights pre-transposed [col][k].
//   Wave w owns rows 16w..16w+15; lane l: g=l>>4, m=l&15.
//   A-frag: row=m, k=g*8+kk*32 (8 contiguous bf16 = 1 ds_read_b128).
//   B-frag: col=m, same k pattern from W^T.
//   C/D: col=m, row=4g+reg (m89-verified layout).
//   LN over 64 channels = 4-reg sum + shfl_xor(1,2,4,8) within 16-lane group.

typedef __bf16 bf16x8 __attribute__((ext_vector_type(8)));
typedef short  s16x8  __attribute__((ext_vector_type(8)));
typedef float  f32x4  __attribute__((ext_vector_type(4)));

#define SWZ(b) ((b) ^ ((((b) >> 7) & 7) << 4))
#define MAXSEG 16

__device__ __forceinline__ unsigned short f2b(float f) {
  union { __hip_bfloat16 h; unsigned short u; } c;
  c.h = __float2bfloat16(f);
  return c.u;
}
__device__ __forceinline__ unsigned int pack2(float a, float b) {
  return (unsigned int)f2b(a) | ((unsigned int)f2b(b) << 16);
}

// stage W[k][c] (64x64 fp32 row-major, global) -> dst = W^T [c][k] bf16, swizzled
__device__ __forceinline__ void stage_wt(const float* __restrict__ W, char* dst, int tid) {
  for (int idx = tid; idx < 2048; idx += 256) {
    int c  = idx >> 5;
    int k2 = (idx & 31) << 1;
    float v0 = W[k2 * 64 + c];
    float v1 = W[(k2 + 1) * 64 + c];
    int byte = c * 128 + k2 * 2;
    *(unsigned int*)(dst + SWZ(byte)) = pack2(v0, v1);
  }
}

// 64-row-tile GEMM, this wave's 16 rows (ew..ew+15) x 64 cols, K=64.
// acc[t] covers cols t*16..t*16+15 in C/D layout.
__device__ __forceinline__ void gemm64(const char* actb, const char* wb,
                                       int ew, int g, int m, f32x4 acc[4]) {
  #pragma unroll
  for (int kk = 0; kk < 2; kk++) {
    s16x8 af = *(const s16x8*)(actb + SWZ((ew + m) * 128 + g * 16 + kk * 64));
    #pragma unroll
    for (int t = 0; t < 4; t++) {
      s16x8 bf = *(const s16x8*)(wb + SWZ((t * 16 + m) * 128 + g * 16 + kk * 64));
      acc[t] = __builtin_amdgcn_mfma_f32_16x16x32_bf16(
          __builtin_bit_cast(bf16x8, af), __builtin_bit_cast(bf16x8, bf), acc[t], 0, 0, 0);
    }
  }
}

// ---------------- node linears (MFMA) ----------------
__global__ __launch_bounds__(256, 3) void node_mfma_kernel(
    const float* __restrict__ x,
    const float* __restrict__ W_in, const float* __restrict__ b_in,
    const float* __restrict__ W_lin, const float* __restrict__ W_src, const float* __restrict__ W_dst,
    float* __restrict__ a_src, float* __restrict__ a_dst, float* __restrict__ vv,
    int N)
{
  __shared__ __align__(16) char sWinT[8192], sWsT[8192], sWdT[8192], sWlT[8192], sX[8192];
  __shared__ float sB[64];
  int tid = threadIdx.x;
  stage_wt(W_in,  sWinT, tid);
  stage_wt(W_src, sWsT,  tid);
  stage_wt(W_dst, sWdT,  tid);
  stage_wt(W_lin, sWlT,  tid);
  if (tid < 64) sB[tid] = b_in[tid];

  const int lane = tid & 63, wv = tid >> 6;
  const int g = lane >> 4, m = lane & 15;
  const int ew = wv << 4;
  const int srow = tid >> 2, sc0 = (tid & 3) << 4;   // staging map
  const int ntile = (N + 63) >> 6;

  for (int tile = blockIdx.x; tile < ntile; tile += gridDim.x) {
    const int rbase = tile << 6;
    __syncthreads();
    {
      int gr = rbase + srow; if (gr >= N) gr = N - 1;
      const float4* src = (const float4*)&x[(size_t)gr * 64 + sc0];
      #pragma unroll
      for (int q = 0; q < 4; q++) {
        float4 f = src[q];
        int byte = srow * 128 + sc0 * 2 + q * 8;
        *(unsigned int*)(sX + SWZ(byte))     = pack2(f.x, f.y);
        *(unsigned int*)(sX + SWZ(byte + 4)) = pack2(f.z, f.w);
      }
    }
    __syncthreads();

    f32x4 a0[4] = {};
    gemm64(sX, sWinT, ew, g, m, a0);
    float x1[4][4];
    #pragma unroll
    for (int t = 0; t < 4; t++)
      #pragma unroll
      for (int r = 0; r < 4; r++) x1[t][r] = fmaxf(a0[t][r] + sB[t * 16 + m], 0.f);
    __syncthreads();   // done reading sX
    #pragma unroll
    for (int t = 0; t < 4; t++)
      #pragma unroll
      for (int r = 0; r < 4; r++)
        *(unsigned short*)(sX + SWZ((ew + 4 * g + r) * 128 + (t * 16 + m) * 2)) = f2b(x1[t][r]);
    __syncthreads();

    f32x4 as[4] = {}, ad[4] = {}, al[4] = {};
    gemm64(sX, sWsT, ew, g, m, as);
    gemm64(sX, sWdT, ew, g, m, ad);
    gemm64(sX, sWlT, ew, g, m, al);
    #pragma unroll
    for (int t = 0; t < 4; t++)
      #pragma unroll
      for (int r = 0; r < 4; r++) {
        int gr = rbase + ew + 4 * g + r;
        if (gr < N) {
          size_t o = (size_t)gr * 64 + t * 16 + m;
          a_src[o] = as[t][r]; a_dst[o] = ad[t][r]; vv[o] = al[t][r];
        }
      }
  }
}

// ---------------- CSR build ----------------
__global__ void hist_kernel(const int* __restrict__ ei, int* __restrict__ deg, int E, int Etot) {
  int stride = gridDim.x * blockDim.x;
  for (int e = blockIdx.x * blockDim.x + threadIdx.x; e < Etot; e += stride) {
    int d = (e < E) ? ei[E + e] : (e - E);
    atomicAdd(&deg[d], 1);
  }
}

__global__ __launch_bounds__(256) void scanA_kernel(const int* __restrict__ deg, int* __restrict__ chunkSum, int N) {
  __shared__ int s[256];
  int i = blockIdx.x * 256 + threadIdx.x;
  s[threadIdx.x] = (i < N) ? deg[i] : 0;
  __syncthreads();
  for (int off = 128; off > 0; off >>= 1) {
    if (threadIdx.x < off) s[threadIdx.x] += s[threadIdx.x + off];
    __syncthreads();
  }
  if (threadIdx.x == 0) chunkSum[blockIdx.x] = s[0];
}

__global__ __launch_bounds__(256) void scanB_kernel(const int* __restrict__ chunkSum, int* __restrict__ chunkPre, int nchunk) {
  __shared__ int s[256];
  int t = threadIdx.x;
  int v = (t < nchunk) ? chunkSum[t] : 0;
  s[t] = v; __syncthreads();
  for (int off = 1; off < 256; off <<= 1) {
    int x = (t >= off) ? s[t - off] : 0;
    __syncthreads();
    s[t] += x;
    __syncthreads();
  }
  if (t < nchunk) chunkPre[t] = s[t] - v;
}

__global__ __launch_bounds__(256) void scanC_kernel(const int* __restrict__ deg, const int* __restrict__ chunkPre,
                                                    int* __restrict__ cursor, int N) {
  __shared__ int s[256];
  int t = threadIdx.x;
  int i = blockIdx.x * 256 + t;
  int v = (i < N) ? deg[i] : 0;
  s[t] = v; __syncthreads();
  for (int off = 1; off < 256; off <<= 1) {
    int x = (t >= off) ? s[t - off] : 0;
    __syncthreads();
    s[t] += x;
    __syncthreads();
  }
  if (i < N) cursor[i] = chunkPre[blockIdx.x] + s[t] - v;
}

__global__ void scatter_kernel(const int* __restrict__ ei, int* __restrict__ cursor, int* __restrict__ perm,
                               int E, int Etot) {
  int stride = gridDim.x * blockDim.x;
  for (int e = blockIdx.x * blockDim.x + threadIdx.x; e < Etot; e += stride) {
    int d = (e < E) ? ei[E + e] : (e - E);
    int p = atomicAdd(&cursor[d], 1);
    perm[p] = e;
  }
}

// ---------------- fused edge kernel (MFMA) ----------------
__global__ __launch_bounds__(256, 3) void edge_kernel(
    const float* __restrict__ pos, const int* __restrict__ ei, const int* __restrict__ perm,
    const float* __restrict__ a_src_g, const float* __restrict__ a_dst_g, const float* __restrict__ v_g,
    const float* __restrict__ pos_W1, const float* __restrict__ pos_b1,
    const float* __restrict__ pos_gg, const float* __restrict__ pos_beta,
    const float* __restrict__ pos_W2, const float* __restrict__ pos_b2,
    const float* __restrict__ att_W1, const float* __restrict__ att_b1,
    const float* __restrict__ att_gg, const float* __restrict__ att_beta,
    const float* __restrict__ att_W2, const float* __restrict__ att_b2,
    float* __restrict__ numer, float* __restrict__ denom,
    int E, int Etot)
{
  __shared__ __align__(16) char sW2t[8192], sA1t[8192], sA2t[8192], sAct[8192];
  __shared__ float sAccN[MAXSEG * 64], sAccD[MAXSEG * 64];
  __shared__ float sPW1[192];
  __shared__ float sPB1[64], sPG[64], sPBeta[64], sPB2[64];
  __shared__ float sAB1[64], sAG[64], sABeta[64], sAB2[64];
  __shared__ int   sS[64], sD[64], sSeg[64];
  __shared__ int   sUd[MAXSEG];
  __shared__ int   sNseg;
  __shared__ float sPD[3][64];

  int tid = threadIdx.x;
  stage_wt(pos_W2, sW2t, tid);
  stage_wt(att_W1, sA1t, tid);
  stage_wt(att_W2, sA2t, tid);
  for (int i = tid; i < 192; i += 256) sPW1[i] = pos_W1[i];
  if (tid < 64) {
    sPB1[tid] = pos_b1[tid]; sPG[tid] = pos_gg[tid]; sPBeta[tid] = pos_beta[tid]; sPB2[tid] = pos_b2[tid];
    sAB1[tid] = att_b1[tid]; sAG[tid] = att_gg[tid]; sABeta[tid] = att_beta[tid]; sAB2[tid] = att_b2[tid];
  }

  const int lane = tid & 63, wv = tid >> 6;
  const int g = lane >> 4, m = lane & 15;
  const int ew = wv << 4;
  const int ntile = (Etot + 63) >> 6;

  for (int tile = blockIdx.x; tile < ntile; tile += gridDim.x) {
    const int ebase = tile << 6;
    __syncthreads();  // prev tile fully flushed

    for (int i = tid; i < MAXSEG * 64; i += 256) { sAccN[i] = 0.f; sAccD[i] = 0.f; }

    if (tid < 64) {
      int slot = ebase + tid;
      int s = 0, d = -1;
      if (slot < Etot) {
        int e = perm[slot];
        if (e < E) { s = ei[e]; d = ei[E + e]; }
        else       { s = e - E; d = s; }
      }
      sS[tid] = s; sD[tid] = d;
      int dm = d < 0 ? 0 : d;
      sPD[0][tid] = pos[dm * 3 + 0] - pos[s * 3 + 0];
      sPD[1][tid] = pos[dm * 3 + 1] - pos[s * 3 + 1];
      sPD[2][tid] = pos[dm * 3 + 2] - pos[s * 3 + 2];
    }
    __syncthreads();

    if (tid < 64) {  // wave 0: segment ids via ballot
      bool valid = sD[tid] >= 0;
      bool flag  = valid && (tid == 0 || sD[tid] != sD[tid - 1]);
      unsigned long long bm = __ballot(flag);
      int cnt = __popcll(bm << (63 - tid));
      sSeg[tid] = valid ? (cnt - 1) : -1;
      if (flag && (cnt - 1) < MAXSEG) sUd[cnt - 1] = sD[tid];
      if (tid == 0) sNseg = __popcll(bm);
    }

    // ---- Phase A (VALU): h = relu(LN(pd @ posW1 + b1)) -> sAct bf16 ----
    {
      float h[4][4];  // [t][r]
      #pragma unroll
      for (int r = 0; r < 4; r++) {
        int er = ew + 4 * g + r;
        float p0 = sPD[0][er], p1 = sPD[1][er], p2 = sPD[2][er];
        #pragma unroll
        for (int t = 0; t < 4; t++) {
          int c = t * 16 + m;
          h[t][r] = fmaf(p0, sPW1[c], fmaf(p1, sPW1[64 + c], fmaf(p2, sPW1[128 + c], sPB1[c])));
        }
      }
      #pragma unroll
      for (int r = 0; r < 4; r++) {
        float s = h[0][r] + h[1][r] + h[2][r] + h[3][r];
        s += __shfl_xor(s, 1); s += __shfl_xor(s, 2); s += __shfl_xor(s, 4); s += __shfl_xor(s, 8);
        float mean = s * (1.f / 64.f);
        float q = 0.f;
        #pragma unroll
        for (int t = 0; t < 4; t++) { float dd = h[t][r] - mean; q = fmaf(dd, dd, q); }
        q += __shfl_xor(q, 1); q += __shfl_xor(q, 2); q += __shfl_xor(q, 4); q += __shfl_xor(q, 8);
        float rs = rsqrtf(q * (1.f / 64.f) + 1e-5f);
        #pragma unroll
        for (int t = 0; t < 4; t++) {
          int c = t * 16 + m;
          float val = fmaxf(fmaf((h[t][r] - mean) * rs, sPG[c], sPBeta[c]), 0.f);
          *(unsigned short*)(sAct + SWZ((ew + 4 * g + r) * 128 + c * 2)) = f2b(val);
        }
      }
    }
    __syncthreads();

    // ---- GEMM1: delta = H @ posW2 + b2 ----
    f32x4 dacc[4] = {};
    gemm64(sAct, sW2t, ew, g, m, dacc);
    float del[4][4];
    #pragma unroll
    for (int t = 0; t < 4; t++)
      #pragma unroll
      for (int r = 0; r < 4; r++) del[t][r] = dacc[t][r] + sPB2[t * 16 + m];
    __syncthreads();  // done reading sAct(H)

    // ---- attin = a_dst[d] - a_src[s] + delta -> sAct bf16 ----
    #pragma unroll
    for (int r = 0; r < 4; r++) {
      int er = ew + 4 * g + r;
      int s = sS[er], d = sD[er];
      int dm = d < 0 ? 0 : d;
      #pragma unroll
      for (int t = 0; t < 4; t++) {
        int c = t * 16 + m;
        float a = a_dst_g[(size_t)dm * 64 + c] - a_src_g[(size_t)s * 64 + c] + del[t][r];
        *(unsigned short*)(sAct + SWZ(er * 128 + c * 2)) = f2b(a);
      }
    }
    __syncthreads();

    // ---- GEMM2 + LN: h2 = relu(LN(attin @ attW1 + b1)) ----
    f32x4 acc2[4] = {};
    gemm64(sAct, sA1t, ew, g, m, acc2);
    float h2[4][4];
    #pragma unroll
    for (int t = 0; t < 4; t++)
      #pragma unroll
      for (int r = 0; r < 4; r++) h2[t][r] = acc2[t][r] + sAB1[t * 16 + m];
    #pragma unroll
    for (int r = 0; r < 4; r++) {
      float s = h2[0][r] + h2[1][r] + h2[2][r] + h2[3][r];
      s += __shfl_xor(s, 1); s += __shfl_xor(s, 2); s += __shfl_xor(s, 4); s += __shfl_xor(s, 8);
      float mean = s * (1.f / 64.f);
      float q = 0.f;
      #pragma unroll
      for (int t = 0; t < 4; t++) { float dd = h2[t][r] - mean; q = fmaf(dd, dd, q); }
      q += __shfl_xor(q, 1); q += __shfl_xor(q, 2); q += __shfl_xor(q, 4); q += __shfl_xor(q, 8);
      float rs = rsqrtf(q * (1.f / 64.f) + 1e-5f);
      #pragma unroll
      for (int t = 0; t < 4; t++) {
        int c = t * 16 + m;
        h2[t][r] = fmaxf(fmaf((h2[t][r] - mean) * rs, sAG[c], sABeta[c]), 0.f);
      }
    }
    __syncthreads();  // all waves done reading sAct(attin)
    #pragma unroll
    for (int t = 0; t < 4; t++)
      #pragma unroll
      for (int r = 0; r < 4; r++)
        *(unsigned short*)(sAct + SWZ((ew + 4 * g + r) * 128 + (t * 16 + m) * 2)) = f2b(h2[t][r]);
    __syncthreads();

    // ---- GEMM3: alpha = h2 @ attW2; exp; segmented accumulate ----
    f32x4 acc3[4] = {};
    gemm64(sAct, sA2t, ew, g, m, acc3);

    {
      int curseg = -1, curd = 0;
      float aN[4] = {0.f, 0.f, 0.f, 0.f}, aD[4] = {0.f, 0.f, 0.f, 0.f};
      #pragma unroll
      for (int r = 0; r < 4; r++) {
        int er = ew + 4 * g + r;
        int d = sD[er];
        if (d < 0) continue;
        int seg = sSeg[er];
        if (seg != curseg) {
          if (curseg >= 0) {
            if (curseg < MAXSEG) {
              #pragma unroll
              for (int t = 0; t < 4; t++) {
                atomicAdd(&sAccN[curseg * 64 + t * 16 + m], aN[t]);
                atomicAdd(&sAccD[curseg * 64 + t * 16 + m], aD[t]);
              }
            } else {
              #pragma unroll
              for (int t = 0; t < 4; t++) {
                atomicAdd(&numer[(size_t)curd * 64 + t * 16 + m], aN[t]);
                atomicAdd(&denom[(size_t)curd * 64 + t * 16 + m], aD[t]);
              }
            }
          }
          curseg = seg; curd = d;
          #pragma unroll
          for (int t = 0; t < 4; t++) { aN[t] = 0.f; aD[t] = 0.f; }
        }
        int s = sS[er];
        #pragma unroll
        for (int t = 0; t < 4; t++) {
          int c = t * 16 + m;
          float ee = __expf(acc3[t][r] + sAB2[c]);
          float vvl = v_g[(size_t)s * 64 + c];
          aN[t] = fmaf(ee, vvl + del[t][r], aN[t]);
          aD[t] += ee;
        }
      }
      if (curseg >= 0) {
        if (curseg < MAXSEG) {
          #pragma unroll
          for (int t = 0; t < 4; t++) {
            atomicAdd(&sAccN[curseg * 64 + t * 16 + m], aN[t]);
            atomicAdd(&sAccD[curseg * 64 + t * 16 + m], aD[t]);
          }
        } else {
          #pragma unroll
          for (int t = 0; t < 4; t++) {
            atomicAdd(&numer[(size_t)curd * 64 + t * 16 + m], aN[t]);
            atomicAdd(&denom[(size_t)curd * 64 + t * 16 + m], aD[t]);
          }
        }
      }
    }
    __syncthreads();

    int nseg = sNseg; if (nseg > MAXSEG) nseg = MAXSEG;
    for (int idx = tid; idx < nseg * 64; idx += 256) {
      int seg = idx >> 6, c = idx & 63;
      int d = sUd[seg];
      atomicAdd(&numer[(size_t)d * 64 + c], sAccN[idx]);
      atomicAdd(&denom[(size_t)d * 64 + c], sAccD[idx]);
    }
  }
}

// ---------------- output linear (MFMA) ----------------
__global__ __launch_bounds__(256) void out_mfma_kernel(
    const float* __restrict__ numer, const float* __restrict__ denom,
    const float* __restrict__ W_out, const float* __restrict__ b_out,
    float* __restrict__ out, int N)
{
  __shared__ __align__(16) char sWoT[8192], sX[8192];
  __shared__ float sB[64];
  int tid = threadIdx.x;
  stage_wt(W_out, sWoT, tid);
  if (tid < 64) sB[tid] = b_out[tid];

  const int lane = tid & 63, wv = tid >> 6;
  const int g = lane >> 4, m = lane & 15;
  const int ew = wv << 4;
  const int srow = tid >> 2, sc0 = (tid & 3) << 4;
  const int ntile = (N + 63) >> 6;

  for (int tile = blockIdx.x; tile < ntile; tile += gridDim.x) {
    const int rbase = tile << 6;
    __syncthreads();
    {
      int gr = rbase + srow; if (gr >= N) gr = N - 1;
      const float4* nsrc = (const float4*)&numer[(size_t)gr * 64 + sc0];
      const float4* dsrc = (const float4*)&denom[(size_t)gr * 64 + sc0];
      #pragma unroll
      for (int q = 0; q < 4; q++) {
        float4 fn = nsrc[q], fd = dsrc[q];
        float m0 = fn.x / fmaxf(fd.x, 1e-16f);
        float m1 = fn.y / fmaxf(fd.y, 1e-16f);
        float m2 = fn.z / fmaxf(fd.z, 1e-16f);
        float m3 = fn.w / fmaxf(fd.w, 1e-16f);
        int byte = srow * 128 + sc0 * 2 + q * 8;
        *(unsigned int*)(sX + SWZ(byte))     = pack2(m0, m1);
        *(unsigned int*)(sX + SWZ(byte + 4)) = pack2(m2, m3);
      }
    }
    __syncthreads();
    f32x4 acc[4] = {};
    gemm64(sX, sWoT, ew, g, m, acc);
    #pragma unroll
    for (int t = 0; t < 4; t++)
      #pragma unroll
      for (int r = 0; r < 4; r++) {
        int gr = rbase + ew + 4 * g + r;
        if (gr < N) out[(size_t)gr * 64 + t * 16 + m] = fmaxf(acc[t][r] + sB[t * 16 + m], 0.f);
      }
  }
}

extern "C" void kernel_launch(void* const* d_in, const int* in_sizes, int n_in,
                              void* d_out, int out_size, void* d_ws, size_t ws_size,
                              hipStream_t stream) {
  (void)n_in; (void)out_size; (void)ws_size;
  const float* x        = (const float*)d_in[0];
  const float* pos      = (const float*)d_in[1];
  const int*   ei       = (const int*)  d_in[2];
  const float* W_in     = (const float*)d_in[3];
  const float* b_in     = (const float*)d_in[4];
  const float* W_lin    = (const float*)d_in[5];
  const float* W_src    = (const float*)d_in[6];
  const float* W_dst    = (const float*)d_in[7];
  const float* pos_W1   = (const float*)d_in[8];
  const float* pos_b1   = (const float*)d_in[9];
  const float* pos_g    = (const float*)d_in[10];
  const float* pos_beta = (const float*)d_in[11];
  const float* pos_W2   = (const float*)d_in[12];
  const float* pos_b2   = (const float*)d_in[13];
  const float* att_W1   = (const float*)d_in[14];
  const float* att_b1   = (const float*)d_in[15];
  const float* att_g    = (const float*)d_in[16];
  const float* att_beta = (const float*)d_in[17];
  const float* att_W2   = (const float*)d_in[18];
  const float* att_b2   = (const float*)d_in[19];
  const float* W_out    = (const float*)d_in[20];
  const float* b_out    = (const float*)d_in[21];

  const int N    = in_sizes[0] / 64;
  const int E    = in_sizes[2] / 2;
  const int Etot = E + N;
  const size_t N64 = (size_t)N * 64;

  float* a_src = (float*)d_ws;
  float* a_dst = a_src + N64;
  float* v     = a_dst + N64;
  float* numer = v + N64;
  float* denom = numer + N64;
  int* deg      = (int*)(denom + N64);
  int* cursor   = deg + N;
  int* chunkSum = cursor + N;
  int* chunkPre = chunkSum + 256;
  int* perm     = chunkPre + 256;

  const int nchunk = (N + 255) / 256;

  hipMemsetAsync(deg, 0, (size_t)N * sizeof(int), stream);
  hipMemsetAsync(numer, 0, 2 * N64 * sizeof(float), stream);

  hist_kernel<<<1024, 256, 0, stream>>>(ei, deg, E, Etot);
  scanA_kernel<<<nchunk, 256, 0, stream>>>(deg, chunkSum, N);
  scanB_kernel<<<1, 256, 0, stream>>>(chunkSum, chunkPre, nchunk);
  scanC_kernel<<<nchunk, 256, 0, stream>>>(deg, chunkPre, cursor, N);
  scatter_kernel<<<1024, 256, 0, stream>>>(ei, cursor, perm, E, Etot);

  const int ntileN = (N + 63) / 64;
  const int nblkN  = ntileN < 768 ? ntileN : 768;
  node_mfma_kernel<<<nblkN, 256, 0, stream>>>(x, W_in, b_in, W_lin, W_src, W_dst,
                                              a_src, a_dst, v, N);

  const int ntile = (Etot + 63) / 64;
  const int nblk  = ntile < 768 ? ntile : 768;
  edge_kernel<<<nblk, 256, 0, stream>>>(pos, ei, perm, a_src, a_dst, v,
      pos_W1, pos_b1, pos_g, pos_beta, pos_W2, pos_b2,
      att_W1, att_b1, att_g, att_beta, att_W2, att_b2,
      numer, denom, E, Etot);

  out_mfma_kernel<<<nblkN, 256, 0, stream>>>(numer, denom, W_out, b_out, (float*)d_out, N);
}